// Round 4
// baseline (1961.219 us; speedup 1.0000x reference)
//
#include <hip/hip_runtime.h>

#define NB 8
#define NP 16384
#define NC 256
#define NH 128
#define NM 4096
#define NS 1024

// ---------- helpers ----------
__device__ __forceinline__ unsigned long long make_key(float v, int n) {
  unsigned u = __float_as_uint(v);
  u = (u & 0x80000000u) ? ~u : (u | 0x80000000u);  // map float -> ascending uint
  unsigned d = ~u;                                 // descending
  return (((unsigned long long)d) << 32) | (unsigned)n;
}

// ---------- transpose [H,C] -> [C,H] for both MLP weights ----------
__global__ __launch_bounds__(256) void transpose_w_kernel(
    const float* __restrict__ wseg, const float* __restrict__ wvote,
    float* __restrict__ tseg, float* __restrict__ tvote) {
  int i = blockIdx.x * 256 + threadIdx.x;  // 0..32767
  int c = i >> 7, o = i & 127;
  tseg[i] = wseg[o * NC + c];
  tvote[i] = wvote[o * NC + c];
}

// ---------- seg branch ----------
// h[o,n] = relu((sum_c w1[o,c]*f[c,n])*scale[o]+bias[o]); S[n]=sum_o h[o,n]
// seg[k,n] = w2[k]*S[n]+b2 ; score[n] = sigmoid((S>=0?max(w2):min(w2))*S+b2)
__global__ __launch_bounds__(256) void seg_kernel(
    const float* __restrict__ features, const float* __restrict__ w1t,
    const float* __restrict__ scale1, const float* __restrict__ bias1,
    const float* __restrict__ w2, const float* __restrict__ b2,
    float* __restrict__ seg_out, unsigned long long* __restrict__ keys) {
  __shared__ float wt[32][128];
  __shared__ float ft[32][64];
  __shared__ float red[16][64];
  __shared__ float Ssh[64];
  __shared__ float w2sh[128];
  int b = blockIdx.y;
  int n0 = blockIdx.x * 64;
  int tid = threadIdx.x;
  int lane = tid & 63;
  int ro = tid >> 4, rc = tid & 15;
  // wave-parallel max/min of w2 (wave 0's copy is the one used later)
  float a0 = w2[lane], a1 = w2[lane + 64];
  float whi = fmaxf(a0, a1), wlo = fminf(a0, a1);
#pragma unroll
  for (int off = 32; off >= 1; off >>= 1) {
    whi = fmaxf(whi, __shfl_xor(whi, off, 64));
    wlo = fminf(wlo, __shfl_xor(wlo, off, 64));
  }
  if (tid < 128) w2sh[tid] = w2[tid];
  const float* fb = features + (size_t)b * NC * NP;
  float acc[8][4] = {};
  for (int kc = 0; kc < NC; kc += 32) {
    for (int q = tid; q < 4096; q += 256) {
      int kk = q >> 7, o = q & 127;
      wt[kk][o] = w1t[(kc + kk) * NH + o];
    }
    for (int q = tid; q < 2048; q += 256) {
      int kk = q >> 6, nn = q & 63;
      ft[kk][nn] = fb[(size_t)(kc + kk) * NP + n0 + nn];
    }
    __syncthreads();
#pragma unroll
    for (int kk = 0; kk < 32; ++kk) {
      float wv[8], fv[4];
#pragma unroll
      for (int i = 0; i < 8; ++i) wv[i] = wt[kk][ro * 8 + i];
#pragma unroll
      for (int j = 0; j < 4; ++j) fv[j] = ft[kk][rc * 4 + j];
#pragma unroll
      for (int i = 0; i < 8; ++i)
#pragma unroll
        for (int j = 0; j < 4; ++j) acc[i][j] = fmaf(wv[i], fv[j], acc[i][j]);
    }
    __syncthreads();
  }
  float part[4] = {};
#pragma unroll
  for (int i = 0; i < 8; ++i) {
    int o = ro * 8 + i;
    float sc = scale1[o], bi = bias1[o];
#pragma unroll
    for (int j = 0; j < 4; ++j) {
      float h = fmaxf(fmaf(acc[i][j], sc, bi), 0.0f);
      part[j] += h;
    }
  }
#pragma unroll
  for (int j = 0; j < 4; ++j) red[ro][rc * 4 + j] = part[j];
  __syncthreads();
  float b2v = b2[0];
  if (tid < 64) {
    float S = 0.0f;
#pragma unroll
    for (int r = 0; r < 16; ++r) S += red[r][tid];
    Ssh[tid] = S;
    float m = (S >= 0.0f ? whi * S : wlo * S) + b2v;
    float sig = 1.0f / (1.0f + expf(-m));
    int nn = n0 + tid;
    keys[(size_t)b * NP + nn] = make_key(sig, nn);
  }
  __syncthreads();
  int n = tid & 63, kg = tid >> 6;
  float S = Ssh[n];
  size_t base = ((size_t)b * 128 + (size_t)kg * 32) * NP + n0 + n;
#pragma unroll
  for (int kk = 0; kk < 32; ++kk)
    seg_out[base + (size_t)kk * NP] = fmaf(w2sh[kg * 32 + kk], S, b2v);
}

// ---------- bitonic sort of each 8192-key chunk (chunk0 asc, chunk1 desc) ----------
__global__ __launch_bounds__(1024) void sort8k_kernel(unsigned long long* __restrict__ keys) {
  __shared__ unsigned long long sk[8192];
  int chunk = blockIdx.x & 1, b = blockIdx.x >> 1;
  bool desc = (chunk == 1);
  unsigned long long* K = keys + (size_t)b * NP + chunk * 8192;
  int tid = threadIdx.x;
  for (int i = tid; i < 8192; i += 1024) sk[i] = K[i];
  __syncthreads();
  for (int k = 2; k <= 8192; k <<= 1) {
    for (int j = k >> 1; j > 0; j >>= 1) {
      for (int i = tid; i < 8192; i += 1024) {
        int ixj = i ^ j;
        if (ixj > i) {
          bool up = (((i & k) == 0) != desc);
          unsigned long long a = sk[i], c = sk[ixj];
          if ((a > c) == up) { sk[i] = c; sk[ixj] = a; }
        }
      }
      __syncthreads();
    }
  }
  for (int i = tid; i < 8192; i += 1024) K[i] = sk[i];
}

// ---------- bitonic merge of lower half: exact top-4096 in sorted order ----------
__global__ __launch_bounds__(1024) void merge_topk_kernel(
    const unsigned long long* __restrict__ keys, int* __restrict__ fg_idx,
    float* __restrict__ fg_xyz, const float* __restrict__ xyz) {
  __shared__ unsigned long long sk[8192];
  int b = blockIdx.x;
  const unsigned long long* K = keys + (size_t)b * NP;
  int tid = threadIdx.x;
  for (int i = tid; i < 8192; i += 1024) {
    unsigned long long a = K[i], c = K[i + 8192];
    sk[i] = (a < c) ? a : c;
  }
  __syncthreads();
  for (int j = 4096; j > 0; j >>= 1) {
    for (int i = tid; i < 8192; i += 1024) {
      int ixj = i ^ j;
      if (ixj > i) {
        unsigned long long a = sk[i], c = sk[ixj];
        if (a > c) { sk[i] = c; sk[ixj] = a; }
      }
    }
    __syncthreads();
  }
  for (int m = tid; m < NM; m += 1024) {
    unsigned long long key = sk[m];
    int idx = (int)(key & 0xffffffffULL);
    fg_idx[b * NM + m] = idx;
    size_t src = ((size_t)b * NP + idx) * 3;
    size_t dst = ((size_t)b * NM + m) * 3;
    fg_xyz[dst + 0] = xyz[src + 0];
    fg_xyz[dst + 1] = xyz[src + 1];
    fg_xyz[dst + 2] = xyz[src + 2];
  }
}

// ---------- vote branch: gathered GEMM -> vh, reg head, clip, ctr points ----------
__global__ __launch_bounds__(256) void vote_kernel(
    const float* __restrict__ features, const int* __restrict__ fg_idx,
    const float* __restrict__ w1t, const float* __restrict__ scale1,
    const float* __restrict__ bias1, const float* __restrict__ rw,
    const float* __restrict__ rb, const float* __restrict__ fg_xyz,
    float* __restrict__ vh, float* __restrict__ offs, float* __restrict__ fg_ctr) {
  __shared__ float wt[32][128];
  __shared__ float ft[32][64];
  __shared__ float hl[128][65];
  __shared__ int idx_l[64];
  int b = blockIdx.y;
  int m0 = blockIdx.x * 64;
  int tid = threadIdx.x;
  int ro = tid >> 4, rc = tid & 15;
  const float* fb = features + (size_t)b * NC * NP;
  if (tid < 64) idx_l[tid] = fg_idx[b * NM + m0 + tid];
  __syncthreads();
  float acc[8][4] = {};
  for (int kc = 0; kc < NC; kc += 32) {
    for (int q = tid; q < 4096; q += 256) {
      int kk = q >> 7, o = q & 127;
      wt[kk][o] = w1t[(kc + kk) * NH + o];
    }
    for (int q = tid; q < 2048; q += 256) {
      int kk = q >> 6, mm = q & 63;
      ft[kk][mm] = fb[(size_t)(kc + kk) * NP + idx_l[mm]];
    }
    __syncthreads();
#pragma unroll
    for (int kk = 0; kk < 32; ++kk) {
      float wv[8], fv[4];
#pragma unroll
      for (int i = 0; i < 8; ++i) wv[i] = wt[kk][ro * 8 + i];
#pragma unroll
      for (int j = 0; j < 4; ++j) fv[j] = ft[kk][rc * 4 + j];
#pragma unroll
      for (int i = 0; i < 8; ++i)
#pragma unroll
        for (int j = 0; j < 4; ++j) acc[i][j] = fmaf(wv[i], fv[j], acc[i][j]);
    }
    __syncthreads();
  }
#pragma unroll
  for (int i = 0; i < 8; ++i) {
    int o = ro * 8 + i;
    float sc = scale1[o], bi = bias1[o];
#pragma unroll
    for (int j = 0; j < 4; ++j) {
      float h = fmaxf(fmaf(acc[i][j], sc, bi), 0.0f);
      hl[o][rc * 4 + j] = h;
      vh[((size_t)b * NH + o) * NM + m0 + rc * 4 + j] = h;
    }
  }
  __syncthreads();
  if (tid < 64) {
    int m = m0 + tid;
    const float MT[3] = {3.0f, 3.0f, 2.0f};
#pragma unroll
    for (int r = 0; r < 3; ++r) {
      float a = 0.0f;
      for (int o = 0; o < NH; ++o) a = fmaf(rw[r * NH + o], hl[o][tid], a);
      a += rb[r];
      a = fminf(fmaxf(a, -MT[r]), MT[r]);
      size_t p = ((size_t)b * NM + m) * 3 + r;
      offs[p] = a;
      fg_ctr[p] = __fadd_rn(fg_xyz[p], a);
    }
  }
}

// ---------- D-FPS, exact np semantics; 256 thr x 16 contiguous pts ----------
__global__ __launch_bounds__(256) void fps_kernel(
    const float* __restrict__ pts_in, int* __restrict__ out_idx) {
  __shared__ float4 pts[NM];                 // 64 KB
  __shared__ unsigned long long wkey[2][4];  // double-buffered per-wave keys
  __shared__ int sel_list[NS];
  int b = blockIdx.x;
  const float* P = pts_in + (size_t)b * NM * 3;
  int* O = out_idx + b * NS;
  int tid = threadIdx.x;
  for (int m = tid; m < NM; m += 256)
    pts[m] = make_float4(P[m * 3 + 0], P[m * 3 + 1], P[m * 3 + 2], 0.0f);
  __syncthreads();
  float x[16], y[16], z[16], d[16];
  float sx = pts[0].x, sy = pts[0].y, sz = pts[0].z;
#pragma unroll
  for (int i = 0; i < 16; ++i) {
    float4 p = pts[tid * 16 + i];
    x[i] = p.x; y[i] = p.y; z[i] = p.z;
    float dx = __fsub_rn(x[i], sx), dy = __fsub_rn(y[i], sy), dz = __fsub_rn(z[i], sz);
    d[i] = __fadd_rn(__fadd_rn(__fmul_rn(dx, dx), __fmul_rn(dy, dy)), __fmul_rn(dz, dz));
  }
  if (tid == 0) sel_list[0] = 0;
  int lane = tid & 63, wave = tid >> 6;
  for (int it = 1; it < NS; ++it) {
    // local first-max over 16 contiguous points
    float bd = d[0];
    int bi = 0;
#pragma unroll
    for (int i = 1; i < 16; ++i) {
      bool g = d[i] > bd;
      bd = g ? d[i] : bd;
      bi = g ? i : bi;
    }
    // wave max (32-bit), then exact argmin-index via ballot
    float wm = bd;
#pragma unroll
    for (int off = 32; off >= 1; off >>= 1)
      wm = fmaxf(wm, __shfl_xor(wm, off, 64));
    unsigned long long mask = __ballot(bd == wm);
    int wl = __ffsll(mask) - 1;  // lowest lane = lowest global index (contiguous map)
    int cand = __builtin_amdgcn_readlane(tid * 16 + bi, wl);
    if (lane == 0)
      wkey[it & 1][wave] =
          (((unsigned long long)__float_as_uint(wm)) << 32) | (unsigned)(4095 - cand);
    __syncthreads();
    unsigned long long k0 = wkey[it & 1][0], k1 = wkey[it & 1][1];
    unsigned long long k2 = wkey[it & 1][2], k3 = wkey[it & 1][3];
    unsigned long long ka = k0 > k1 ? k0 : k1;
    unsigned long long kb = k2 > k3 ? k2 : k3;
    unsigned long long km = ka > kb ? ka : kb;
    int sel = 4095 - (int)(km & 0xffffffffULL);
    if (tid == 0) sel_list[it] = sel;
    float4 s = pts[sel];
#pragma unroll
    for (int i = 0; i < 16; ++i) {
      float dx = __fsub_rn(x[i], s.x), dy = __fsub_rn(y[i], s.y), dz = __fsub_rn(z[i], s.z);
      float dd = __fadd_rn(__fadd_rn(__fmul_rn(dx, dx), __fmul_rn(dy, dy)), __fmul_rn(dz, dz));
      d[i] = fminf(d[i], dd);
    }
  }
  __syncthreads();
  for (int s2 = tid; s2 < NS; s2 += 256) O[s2] = sel_list[s2];
}

// ---------- agg_feat output ----------
__global__ __launch_bounds__(256) void feat_out_kernel(
    const float* __restrict__ vh, const float* __restrict__ features,
    const int* __restrict__ fg_idx, const int* __restrict__ ori_idx,
    const int* __restrict__ ctr_idx, float* __restrict__ out_feat) {
  int b = blockIdx.z;
  int o = blockIdx.y * 4 + (threadIdx.x >> 6);
  int s = blockIdx.x * 64 + (threadIdx.x & 63);
  float val;
  if (s < NS) {
    int i = ctr_idx[b * NS + s];
    val = vh[((size_t)b * NH + o) * NM + i];
  } else {
    int i = ori_idx[b * NS + (s - NS)];
    int g = fg_idx[b * NM + i];
    val = features[((size_t)b * NC + o) * NP + g];
  }
  out_feat[((size_t)b * NH + o) * (2 * NS) + s] = val;
}

// ---------- xyz / offset / origin outputs ----------
__global__ __launch_bounds__(256) void xyz_out_kernel(
    const float* __restrict__ fg_xyz, const float* __restrict__ fg_ctr,
    const float* __restrict__ offs, const int* __restrict__ ori_idx,
    const int* __restrict__ ctr_idx, float* __restrict__ out_agg,
    float* __restrict__ out_cxyz, float* __restrict__ out_coff,
    float* __restrict__ out_corg) {
  int b = blockIdx.y;
  int s = blockIdx.x * 256 + threadIdx.x;  // 0..2047
  if (s < NS) {
    int i = ctr_idx[b * NS + s];
    size_t src = ((size_t)b * NM + i) * 3;
    size_t d_agg = ((size_t)b * 2 * NS + s) * 3;
    size_t d_s = ((size_t)b * NS + s) * 3;
#pragma unroll
    for (int r = 0; r < 3; ++r) {
      float c = fg_ctr[src + r];
      out_agg[d_agg + r] = c;
      out_cxyz[d_s + r] = c;
      out_coff[d_s + r] = offs[src + r];
      out_corg[d_s + r] = fg_xyz[src + r];
    }
  } else {
    int i = ori_idx[b * NS + (s - NS)];
    size_t src = ((size_t)b * NM + i) * 3;
    size_t d_agg = ((size_t)b * 2 * NS + s) * 3;
#pragma unroll
    for (int r = 0; r < 3; ++r) out_agg[d_agg + r] = fg_xyz[src + r];
  }
}

extern "C" void kernel_launch(void* const* d_in, const int* in_sizes, int n_in,
                              void* d_out, int out_size, void* d_ws, size_t ws_size,
                              hipStream_t stream) {
  const float* xyz = (const float*)d_in[0];
  const float* features = (const float*)d_in[1];
  const float* seg_w1 = (const float*)d_in[2];
  const float* seg_scale1 = (const float*)d_in[3];
  const float* seg_bias1 = (const float*)d_in[4];
  const float* seg_w2 = (const float*)d_in[5];
  const float* seg_b2 = (const float*)d_in[6];
  const float* vote_w1 = (const float*)d_in[7];
  const float* vote_scale1 = (const float*)d_in[8];
  const float* vote_bias1 = (const float*)d_in[9];
  const float* reg_w = (const float*)d_in[10];
  const float* reg_b = (const float*)d_in[11];
  float* out = (float*)d_out;

  char* ws = (char*)d_ws;
  unsigned long long* keys = (unsigned long long*)(ws + 0);  // 1,048,576 B
  int* fg_idx = (int*)(ws + 1048576);                        // 131,072 B
  float* fg_xyz = (float*)(ws + 1179648);                    // 393,216 B
  float* fg_ctr = (float*)(ws + 1572864);                    // 393,216 B
  float* offs = (float*)(ws + 1966080);                      // 393,216 B
  int* ori_idx = (int*)(ws + 2359296);                       // 32,768 B
  int* ctr_idx = (int*)(ws + 2392064);                       // 32,768 B
  float* vh = (float*)(ws + 2424832);                        // 16,777,216 B
  float* w1t_s = (float*)(ws + 19202048);                    // 131,072 B
  float* w1t_v = (float*)(ws + 19333120);                    // 131,072 B (end 19,464,192)

  // outputs (reference return order), seg is [B,128,N]:
  float* out_agg_xyz = out;                  // [8,2048,3]      @ 0
  float* out_agg_feat = out + 49152;         // [8,128,2048]    @ 49152
  float* out_ctr_xyz = out + 2146304;        // [8,1024,3]      @ 2146304
  float* out_ctr_off = out + 2170880;        // [8,1024,3]      @ 2170880
  float* out_ctr_org = out + 2195456;        // [8,1024,3]      @ 2195456
  float* out_seg = out + 2220032;            // [8,128,16384]   @ 2220032

  transpose_w_kernel<<<128, 256, 0, stream>>>(seg_w1, vote_w1, w1t_s, w1t_v);
  seg_kernel<<<dim3(NP / 64, NB), 256, 0, stream>>>(
      features, w1t_s, seg_scale1, seg_bias1, seg_w2, seg_b2, out_seg, keys);
  sort8k_kernel<<<2 * NB, 1024, 0, stream>>>(keys);
  merge_topk_kernel<<<NB, 1024, 0, stream>>>(keys, fg_idx, fg_xyz, xyz);
  fps_kernel<<<NB, 256, 0, stream>>>(fg_xyz, ori_idx);  // overlaps with vote + fps_ctr
  vote_kernel<<<dim3(NM / 64, NB), 256, 0, stream>>>(
      features, fg_idx, w1t_v, vote_scale1, vote_bias1, reg_w, reg_b, fg_xyz,
      vh, offs, fg_ctr);
  fps_kernel<<<NB, 256, 0, stream>>>(fg_ctr, ctr_idx);
  feat_out_kernel<<<dim3(32, 32, NB), 256, 0, stream>>>(
      vh, features, fg_idx, ori_idx, ctr_idx, out_agg_feat);
  xyz_out_kernel<<<dim3(8, NB), 256, 0, stream>>>(
      fg_xyz, fg_ctr, offs, ori_idx, ctr_idx, out_agg_xyz, out_ctr_xyz,
      out_ctr_off, out_ctr_org);
}

// Round 5
// 1053.821 us; speedup vs baseline: 1.8611x; 1.8611x over previous
//
#include <hip/hip_runtime.h>

#define NB 8
#define NP 16384
#define NC 256
#define NH 128
#define NM 4096
#define NS 1024

// ---------- helpers ----------
__device__ __forceinline__ unsigned long long make_key(float v, int n) {
  unsigned u = __float_as_uint(v);
  u = (u & 0x80000000u) ? ~u : (u | 0x80000000u);  // map float -> ascending uint
  unsigned d = ~u;                                 // descending
  return (((unsigned long long)d) << 32) | (unsigned)n;
}

// VALU-only 64-lane max (values >= 0). Canonical GCN DPP reduce:
// xor1, xor2 (quad_perm), xor4 (row_half_mirror), xor8 (row_mirror),
// then row_bcast15 + row_bcast31 accumulate -> lane 63 holds global max.
__device__ __forceinline__ float wave_max_dpp(float v) {
#define DPPMAX(ctrl)                                                            \
  v = fmaxf(v, __int_as_float(__builtin_amdgcn_update_dpp(                      \
                 __float_as_int(v), __float_as_int(v), (ctrl), 0xf, 0xf, false)))
  DPPMAX(0xB1);   // quad_perm [1,0,3,2]  : xor 1
  DPPMAX(0x4E);   // quad_perm [2,3,0,1]  : xor 2
  DPPMAX(0x141);  // row_half_mirror      : xor 4 (quads uniform)
  DPPMAX(0x140);  // row_mirror           : xor 8 (octets uniform)
  DPPMAX(0x142);  // row_bcast15
  DPPMAX(0x143);  // row_bcast31
#undef DPPMAX
  return __int_as_float(__builtin_amdgcn_readlane(__float_as_int(v), 63));
}

// ---------- transpose [H,C] -> [C,H] for both MLP weights ----------
__global__ __launch_bounds__(256) void transpose_w_kernel(
    const float* __restrict__ wseg, const float* __restrict__ wvote,
    float* __restrict__ tseg, float* __restrict__ tvote) {
  int i = blockIdx.x * 256 + threadIdx.x;  // 0..32767
  int c = i >> 7, o = i & 127;
  tseg[i] = wseg[o * NC + c];
  tvote[i] = wvote[o * NC + c];
}

// ---------- seg branch ----------
// h[o,n] = relu((sum_c w1[o,c]*f[c,n])*scale[o]+bias[o]); S[n]=sum_o h[o,n]
// seg[k,n] = w2[k]*S[n]+b2 ; score[n] = sigmoid((S>=0?max(w2):min(w2))*S+b2)
__global__ __launch_bounds__(256) void seg_kernel(
    const float* __restrict__ features, const float* __restrict__ w1t,
    const float* __restrict__ scale1, const float* __restrict__ bias1,
    const float* __restrict__ w2, const float* __restrict__ b2,
    float* __restrict__ seg_out, unsigned long long* __restrict__ keys) {
  __shared__ float wt[32][128];
  __shared__ float ft[32][64];
  __shared__ float red[16][64];
  __shared__ float Ssh[64];
  __shared__ float w2sh[128];
  int b = blockIdx.y;
  int n0 = blockIdx.x * 64;
  int tid = threadIdx.x;
  int lane = tid & 63;
  int ro = tid >> 4, rc = tid & 15;
  // wave-parallel max/min of w2 (wave 0's copy is the one used later)
  float a0 = w2[lane], a1 = w2[lane + 64];
  float whi = fmaxf(a0, a1), wlo = fminf(a0, a1);
#pragma unroll
  for (int off = 32; off >= 1; off >>= 1) {
    whi = fmaxf(whi, __shfl_xor(whi, off, 64));
    wlo = fminf(wlo, __shfl_xor(wlo, off, 64));
  }
  if (tid < 128) w2sh[tid] = w2[tid];
  const float* fb = features + (size_t)b * NC * NP;
  float acc[8][4] = {};
  for (int kc = 0; kc < NC; kc += 32) {
    for (int q = tid; q < 4096; q += 256) {
      int kk = q >> 7, o = q & 127;
      wt[kk][o] = w1t[(kc + kk) * NH + o];
    }
    for (int q = tid; q < 2048; q += 256) {
      int kk = q >> 6, nn = q & 63;
      ft[kk][nn] = fb[(size_t)(kc + kk) * NP + n0 + nn];
    }
    __syncthreads();
#pragma unroll
    for (int kk = 0; kk < 32; ++kk) {
      float wv[8], fv[4];
#pragma unroll
      for (int i = 0; i < 8; ++i) wv[i] = wt[kk][ro * 8 + i];
#pragma unroll
      for (int j = 0; j < 4; ++j) fv[j] = ft[kk][rc * 4 + j];
#pragma unroll
      for (int i = 0; i < 8; ++i)
#pragma unroll
        for (int j = 0; j < 4; ++j) acc[i][j] = fmaf(wv[i], fv[j], acc[i][j]);
    }
    __syncthreads();
  }
  float part[4] = {};
#pragma unroll
  for (int i = 0; i < 8; ++i) {
    int o = ro * 8 + i;
    float sc = scale1[o], bi = bias1[o];
#pragma unroll
    for (int j = 0; j < 4; ++j) {
      float h = fmaxf(fmaf(acc[i][j], sc, bi), 0.0f);
      part[j] += h;
    }
  }
#pragma unroll
  for (int j = 0; j < 4; ++j) red[ro][rc * 4 + j] = part[j];
  __syncthreads();
  float b2v = b2[0];
  if (tid < 64) {
    float S = 0.0f;
#pragma unroll
    for (int r = 0; r < 16; ++r) S += red[r][tid];
    Ssh[tid] = S;
    float m = (S >= 0.0f ? whi * S : wlo * S) + b2v;
    float sig = 1.0f / (1.0f + expf(-m));
    int nn = n0 + tid;
    keys[(size_t)b * NP + nn] = make_key(sig, nn);
  }
  __syncthreads();
  int n = tid & 63, kg = tid >> 6;
  float S = Ssh[n];
  size_t base = ((size_t)b * 128 + (size_t)kg * 32) * NP + n0 + n;
#pragma unroll
  for (int kk = 0; kk < 32; ++kk)
    seg_out[base + (size_t)kk * NP] = fmaf(w2sh[kg * 32 + kk], S, b2v);
}

// ---------- bitonic sort of each 8192-key chunk (chunk0 asc, chunk1 desc) ----------
__global__ __launch_bounds__(1024) void sort8k_kernel(unsigned long long* __restrict__ keys) {
  __shared__ unsigned long long sk[8192];
  int chunk = blockIdx.x & 1, b = blockIdx.x >> 1;
  bool desc = (chunk == 1);
  unsigned long long* K = keys + (size_t)b * NP + chunk * 8192;
  int tid = threadIdx.x;
  for (int i = tid; i < 8192; i += 1024) sk[i] = K[i];
  __syncthreads();
  for (int k = 2; k <= 8192; k <<= 1) {
    for (int j = k >> 1; j > 0; j >>= 1) {
      for (int i = tid; i < 8192; i += 1024) {
        int ixj = i ^ j;
        if (ixj > i) {
          bool up = (((i & k) == 0) != desc);
          unsigned long long a = sk[i], c = sk[ixj];
          if ((a > c) == up) { sk[i] = c; sk[ixj] = a; }
        }
      }
      __syncthreads();
    }
  }
  for (int i = tid; i < 8192; i += 1024) K[i] = sk[i];
}

// ---------- bitonic merge of lower half: exact top-4096 in sorted order ----------
__global__ __launch_bounds__(1024) void merge_topk_kernel(
    const unsigned long long* __restrict__ keys, int* __restrict__ fg_idx,
    float* __restrict__ fg_xyz, const float* __restrict__ xyz) {
  __shared__ unsigned long long sk[8192];
  int b = blockIdx.x;
  const unsigned long long* K = keys + (size_t)b * NP;
  int tid = threadIdx.x;
  for (int i = tid; i < 8192; i += 1024) {
    unsigned long long a = K[i], c = K[i + 8192];
    sk[i] = (a < c) ? a : c;
  }
  __syncthreads();
  for (int j = 4096; j > 0; j >>= 1) {
    for (int i = tid; i < 8192; i += 1024) {
      int ixj = i ^ j;
      if (ixj > i) {
        unsigned long long a = sk[i], c = sk[ixj];
        if (a > c) { sk[i] = c; sk[ixj] = a; }
      }
    }
    __syncthreads();
  }
  for (int m = tid; m < NM; m += 1024) {
    unsigned long long key = sk[m];
    int idx = (int)(key & 0xffffffffULL);
    fg_idx[b * NM + m] = idx;
    size_t src = ((size_t)b * NP + idx) * 3;
    size_t dst = ((size_t)b * NM + m) * 3;
    fg_xyz[dst + 0] = xyz[src + 0];
    fg_xyz[dst + 1] = xyz[src + 1];
    fg_xyz[dst + 2] = xyz[src + 2];
  }
}

// ---------- vote branch: gathered GEMM -> vh, reg head, clip, ctr points ----------
__global__ __launch_bounds__(256) void vote_kernel(
    const float* __restrict__ features, const int* __restrict__ fg_idx,
    const float* __restrict__ w1t, const float* __restrict__ scale1,
    const float* __restrict__ bias1, const float* __restrict__ rw,
    const float* __restrict__ rb, const float* __restrict__ fg_xyz,
    float* __restrict__ vh, float* __restrict__ offs, float* __restrict__ fg_ctr) {
  __shared__ float wt[32][128];
  __shared__ float ft[32][64];
  __shared__ float hl[128][65];
  __shared__ int idx_l[64];
  int b = blockIdx.y;
  int m0 = blockIdx.x * 64;
  int tid = threadIdx.x;
  int ro = tid >> 4, rc = tid & 15;
  const float* fb = features + (size_t)b * NC * NP;
  if (tid < 64) idx_l[tid] = fg_idx[b * NM + m0 + tid];
  __syncthreads();
  float acc[8][4] = {};
  for (int kc = 0; kc < NC; kc += 32) {
    for (int q = tid; q < 4096; q += 256) {
      int kk = q >> 7, o = q & 127;
      wt[kk][o] = w1t[(kc + kk) * NH + o];
    }
    for (int q = tid; q < 2048; q += 256) {
      int kk = q >> 6, mm = q & 63;
      ft[kk][mm] = fb[(size_t)(kc + kk) * NP + idx_l[mm]];
    }
    __syncthreads();
#pragma unroll
    for (int kk = 0; kk < 32; ++kk) {
      float wv[8], fv[4];
#pragma unroll
      for (int i = 0; i < 8; ++i) wv[i] = wt[kk][ro * 8 + i];
#pragma unroll
      for (int j = 0; j < 4; ++j) fv[j] = ft[kk][rc * 4 + j];
#pragma unroll
      for (int i = 0; i < 8; ++i)
#pragma unroll
        for (int j = 0; j < 4; ++j) acc[i][j] = fmaf(wv[i], fv[j], acc[i][j]);
    }
    __syncthreads();
  }
#pragma unroll
  for (int i = 0; i < 8; ++i) {
    int o = ro * 8 + i;
    float sc = scale1[o], bi = bias1[o];
#pragma unroll
    for (int j = 0; j < 4; ++j) {
      float h = fmaxf(fmaf(acc[i][j], sc, bi), 0.0f);
      hl[o][rc * 4 + j] = h;
      vh[((size_t)b * NH + o) * NM + m0 + rc * 4 + j] = h;
    }
  }
  __syncthreads();
  if (tid < 64) {
    int m = m0 + tid;
    const float MT[3] = {3.0f, 3.0f, 2.0f};
#pragma unroll
    for (int r = 0; r < 3; ++r) {
      float a = 0.0f;
      for (int o = 0; o < NH; ++o) a = fmaf(rw[r * NH + o], hl[o][tid], a);
      a += rb[r];
      a = fminf(fmaxf(a, -MT[r]), MT[r]);
      size_t p = ((size_t)b * NM + m) * 3 + r;
      offs[p] = a;
      fg_ctr[p] = __fadd_rn(fg_xyz[p], a);
    }
  }
}

// ---------- D-FPS, exact np semantics; 512 thr x 8 contiguous pts, DPP reduce ----------
#define PPT 8
__global__ __launch_bounds__(512) void fps_kernel(
    const float* __restrict__ fg_xyz, const float* __restrict__ fg_ctr,
    int* __restrict__ ori_idx, int* __restrict__ ctr_idx) {
  __shared__ float4 pts[NM];  // 64 KB
  __shared__ __align__(16) unsigned long long wkey[2][8];
  __shared__ int sel_list[NS];
  int set = blockIdx.x, b = blockIdx.y;
  const float* P = (set == 0 ? fg_xyz : fg_ctr) + (size_t)b * NM * 3;
  int* O = (set == 0 ? ori_idx : ctr_idx) + b * NS;
  int tid = threadIdx.x;
  for (int m = tid; m < NM; m += 512)
    pts[m] = make_float4(P[m * 3 + 0], P[m * 3 + 1], P[m * 3 + 2], 0.0f);
  __syncthreads();
  float x[PPT], y[PPT], z[PPT], d[PPT];
#pragma unroll
  for (int i = 0; i < PPT; ++i) {
    float4 p = pts[tid * PPT + i];
    x[i] = p.x; y[i] = p.y; z[i] = p.z;
    d[i] = 3.402823466e38f;  // fmin(FLT_MAX, dist0) == dist0 bitwise
  }
  if (tid == 0) sel_list[0] = 0;
  int lane = tid & 63, wave = tid >> 6;
  float sx = pts[0].x, sy = pts[0].y, sz = pts[0].z;
  for (int it = 1; it < NS; ++it) {
    // fused: update d with previous selection, track local first-max
    float bd;
    int bi;
#pragma unroll
    for (int i = 0; i < PPT; ++i) {
      float dx = __fsub_rn(x[i], sx), dy = __fsub_rn(y[i], sy), dz = __fsub_rn(z[i], sz);
      float dd = __fadd_rn(__fadd_rn(__fmul_rn(dx, dx), __fmul_rn(dy, dy)), __fmul_rn(dz, dz));
      float nd = fminf(d[i], dd);
      d[i] = nd;
      if (i == 0) { bd = nd; bi = 0; }
      else { bool g = nd > bd; bd = g ? nd : bd; bi = g ? i : bi; }
    }
    // wave max on VALU pipe (DPP), exact first-index via ballot (contiguous map)
    float wm = wave_max_dpp(bd);
    unsigned long long mask = __ballot(bd == wm);
    int wl = __ffsll(mask) - 1;
    int cand = __builtin_amdgcn_readlane(tid * PPT + bi, wl);
    if (lane == 0)
      wkey[it & 1][wave] =
          (((unsigned long long)__float_as_uint(wm)) << 32) | (unsigned)(4095 - cand);
    __syncthreads();
    const ulonglong2* wk = (const ulonglong2*)&wkey[it & 1][0];
    ulonglong2 q0 = wk[0], q1 = wk[1], q2 = wk[2], q3 = wk[3];
    unsigned long long m0 = q0.x > q0.y ? q0.x : q0.y;
    unsigned long long m1 = q1.x > q1.y ? q1.x : q1.y;
    unsigned long long m2 = q2.x > q2.y ? q2.x : q2.y;
    unsigned long long m3 = q3.x > q3.y ? q3.x : q3.y;
    m0 = m0 > m1 ? m0 : m1;
    m2 = m2 > m3 ? m2 : m3;
    unsigned long long km = m0 > m2 ? m0 : m2;
    int sel = 4095 - (int)(km & 0xffffffffULL);
    if (tid == 0) sel_list[it] = sel;
    float4 s = pts[sel];  // broadcast read
    sx = s.x; sy = s.y; sz = s.z;
  }
  __syncthreads();
  for (int s2 = tid; s2 < NS; s2 += 512) O[s2] = sel_list[s2];
}

// ---------- agg_feat output ----------
__global__ __launch_bounds__(256) void feat_out_kernel(
    const float* __restrict__ vh, const float* __restrict__ features,
    const int* __restrict__ fg_idx, const int* __restrict__ ori_idx,
    const int* __restrict__ ctr_idx, float* __restrict__ out_feat) {
  int b = blockIdx.z;
  int o = blockIdx.y * 4 + (threadIdx.x >> 6);
  int s = blockIdx.x * 64 + (threadIdx.x & 63);
  float val;
  if (s < NS) {
    int i = ctr_idx[b * NS + s];
    val = vh[((size_t)b * NH + o) * NM + i];
  } else {
    int i = ori_idx[b * NS + (s - NS)];
    int g = fg_idx[b * NM + i];
    val = features[((size_t)b * NC + o) * NP + g];
  }
  out_feat[((size_t)b * NH + o) * (2 * NS) + s] = val;
}

// ---------- xyz / offset / origin outputs ----------
__global__ __launch_bounds__(256) void xyz_out_kernel(
    const float* __restrict__ fg_xyz, const float* __restrict__ fg_ctr,
    const float* __restrict__ offs, const int* __restrict__ ori_idx,
    const int* __restrict__ ctr_idx, float* __restrict__ out_agg,
    float* __restrict__ out_cxyz, float* __restrict__ out_coff,
    float* __restrict__ out_corg) {
  int b = blockIdx.y;
  int s = blockIdx.x * 256 + threadIdx.x;  // 0..2047
  if (s < NS) {
    int i = ctr_idx[b * NS + s];
    size_t src = ((size_t)b * NM + i) * 3;
    size_t d_agg = ((size_t)b * 2 * NS + s) * 3;
    size_t d_s = ((size_t)b * NS + s) * 3;
#pragma unroll
    for (int r = 0; r < 3; ++r) {
      float c = fg_ctr[src + r];
      out_agg[d_agg + r] = c;
      out_cxyz[d_s + r] = c;
      out_coff[d_s + r] = offs[src + r];
      out_corg[d_s + r] = fg_xyz[src + r];
    }
  } else {
    int i = ori_idx[b * NS + (s - NS)];
    size_t src = ((size_t)b * NM + i) * 3;
    size_t d_agg = ((size_t)b * 2 * NS + s) * 3;
#pragma unroll
    for (int r = 0; r < 3; ++r) out_agg[d_agg + r] = fg_xyz[src + r];
  }
}

extern "C" void kernel_launch(void* const* d_in, const int* in_sizes, int n_in,
                              void* d_out, int out_size, void* d_ws, size_t ws_size,
                              hipStream_t stream) {
  const float* xyz = (const float*)d_in[0];
  const float* features = (const float*)d_in[1];
  const float* seg_w1 = (const float*)d_in[2];
  const float* seg_scale1 = (const float*)d_in[3];
  const float* seg_bias1 = (const float*)d_in[4];
  const float* seg_w2 = (const float*)d_in[5];
  const float* seg_b2 = (const float*)d_in[6];
  const float* vote_w1 = (const float*)d_in[7];
  const float* vote_scale1 = (const float*)d_in[8];
  const float* vote_bias1 = (const float*)d_in[9];
  const float* reg_w = (const float*)d_in[10];
  const float* reg_b = (const float*)d_in[11];
  float* out = (float*)d_out;

  char* ws = (char*)d_ws;
  unsigned long long* keys = (unsigned long long*)(ws + 0);  // 1,048,576 B
  int* fg_idx = (int*)(ws + 1048576);                        // 131,072 B
  float* fg_xyz = (float*)(ws + 1179648);                    // 393,216 B
  float* fg_ctr = (float*)(ws + 1572864);                    // 393,216 B
  float* offs = (float*)(ws + 1966080);                      // 393,216 B
  int* ori_idx = (int*)(ws + 2359296);                       // 32,768 B
  int* ctr_idx = (int*)(ws + 2392064);                       // 32,768 B
  float* vh = (float*)(ws + 2424832);                        // 16,777,216 B
  float* w1t_s = (float*)(ws + 19202048);                    // 131,072 B
  float* w1t_v = (float*)(ws + 19333120);                    // 131,072 B (end 19,464,192)

  // outputs (reference return order), seg is [B,128,N]:
  float* out_agg_xyz = out;                  // [8,2048,3]      @ 0
  float* out_agg_feat = out + 49152;         // [8,128,2048]    @ 49152
  float* out_ctr_xyz = out + 2146304;        // [8,1024,3]      @ 2146304
  float* out_ctr_off = out + 2170880;        // [8,1024,3]      @ 2170880
  float* out_ctr_org = out + 2195456;        // [8,1024,3]      @ 2195456
  float* out_seg = out + 2220032;            // [8,128,16384]   @ 2220032

  transpose_w_kernel<<<128, 256, 0, stream>>>(seg_w1, vote_w1, w1t_s, w1t_v);
  seg_kernel<<<dim3(NP / 64, NB), 256, 0, stream>>>(
      features, w1t_s, seg_scale1, seg_bias1, seg_w2, seg_b2, out_seg, keys);
  sort8k_kernel<<<2 * NB, 1024, 0, stream>>>(keys);
  merge_topk_kernel<<<NB, 1024, 0, stream>>>(keys, fg_idx, fg_xyz, xyz);
  vote_kernel<<<dim3(NM / 64, NB), 256, 0, stream>>>(
      features, fg_idx, w1t_v, vote_scale1, vote_bias1, reg_w, reg_b, fg_xyz,
      vh, offs, fg_ctr);
  // both point-sets in ONE dispatch (16 blocks) so they run concurrently
  fps_kernel<<<dim3(2, NB), 512, 0, stream>>>(fg_xyz, fg_ctr, ori_idx, ctr_idx);
  feat_out_kernel<<<dim3(32, 32, NB), 256, 0, stream>>>(
      vh, features, fg_idx, ori_idx, ctr_idx, out_agg_feat);
  xyz_out_kernel<<<dim3(8, NB), 256, 0, stream>>>(
      fg_xyz, fg_ctr, offs, ori_idx, ctr_idx, out_agg_xyz, out_ctr_xyz,
      out_ctr_off, out_ctr_org);
}